// Round 12
// baseline (116.629 us; speedup 1.0000x reference)
//
#include <hip/hip_runtime.h>
#include <cstdint>

#define NEG_SLOPE 0.2f
#define EPS 1e-16f
#define BSH 7                  // 128 nodes per bucket
#define BNODES (1 << BSH)
#define NBMAX 1024             // supports N <= 131072
#define CAP 2560               // bucket capacity (mean ~1766, +19 sigma)
#define EPT 16                 // edges per thread in bucket pass
#define MAXDEG 64              // padded row (Poisson(12.8)+self-loop << 64)

__device__ __forceinline__ float lrelu(float x) {
    return (x >= 0.f) ? x : NEG_SLOPE * x;
}
__device__ __forceinline__ float wave_sum(float v) {
    #pragma unroll
    for (int o = 32; o; o >>= 1) v += __shfl_xor(v, o);
    return v;
}

// ---- consts + gcur zeroing (rocclr fill kernel costs ~40us/replay) ----
// wave 0: {c0,c1} = W1^T att_s1, {d0,d1} = W1^T att_d1.
__global__ __launch_bounds__(1024)
void const_kernel(const float* __restrict__ W1,
                  const float* __restrict__ as1,
                  const float* __restrict__ ad1,
                  float4* __restrict__ consts,
                  int* __restrict__ gcur) {
    int tid = threadIdx.x;
    gcur[tid] = 0;                       // NBMAX == 1024
    if (tid < 64) {
        float w0 = W1[2 * tid], w1 = W1[2 * tid + 1];
        float s = as1[tid], d = ad1[tid];
        float c0 = wave_sum(w0 * s);
        float c1 = wave_sum(w1 * s);
        float e0 = wave_sum(w0 * d);
        float e1 = wave_sum(w1 * d);
        if (tid == 0) *consts = make_float4(c0, c1, e0, e1);
    }
}

// ---- pass 1: bucket partition by dst>>7, two-read-pass, cached chunked
// stores (L2-merged; NT stores paid 32B/edge — round-9 lesson).
__global__ __launch_bounds__(256)
void bucket_kernel(const int* __restrict__ src, const int* __restrict__ dst,
                   int* __restrict__ gcur, unsigned* __restrict__ bkt,
                   int E, int Etot, int nbuck) {
    __shared__ int cnt[NBMAX];
    __shared__ int base[NBMAX];
    int tid = threadIdx.x;
    int blockBase = blockIdx.x * (256 * EPT);
    for (int b = tid; b < nbuck; b += 256) cnt[b] = 0;
    __syncthreads();

    #pragma unroll
    for (int k = 0; k < EPT; ++k) {
        int i = blockBase + k * 256 + tid;
        if (i < Etot) {
            int d = (i < E) ? dst[i] : (i - E);
            atomicAdd(&cnt[d >> BSH], 1);
        }
    }
    __syncthreads();
    for (int b = tid; b < nbuck; b += 256) {
        int c = cnt[b];
        base[b] = c ? atomicAdd(gcur + b, c) : 0;
    }
    __syncthreads();
    for (int b = tid; b < nbuck; b += 256) cnt[b] = 0;
    __syncthreads();

    #pragma unroll
    for (int k = 0; k < EPT; ++k) {
        int i = blockBase + k * 256 + tid;
        if (i < Etot) {
            int s, d;
            if (i < E) { s = src[i]; d = dst[i]; } else { s = d = i - E; }
            int b = d >> BSH;
            unsigned p = ((unsigned)s << BSH) | (unsigned)(d & (BNODES - 1));
            int pos = base[b] + atomicAdd(&cnt[b], 1);
            if (pos < CAP) bkt[(size_t)b * CAP + pos] = p;   // cached store
        }
    }
}

// ====== fused distrib + layer-1 agg + node2: one block per bucket ======
// Build padded rows for 128 nodes in LDS (no global CSR), then 4 waves
// aggregate 32 nodes each; lane = slot, rows[i][lane] conflict-free.
__global__ __launch_bounds__(256)
void agg1f_kernel(const int* __restrict__ gcur, const unsigned* __restrict__ bkt,
                  const float2* __restrict__ x, const float4* __restrict__ consts,
                  const float* __restrict__ W1, const float* __restrict__ b1,
                  const float* __restrict__ W2, const float* __restrict__ as2,
                  const float* __restrict__ ad2, float4* __restrict__ pack2,
                  int N) {
    __shared__ int rows[BNODES][MAXDEG];   // 32 KB
    __shared__ int cur[BNODES];
    int b = blockIdx.x, tid = threadIdx.x;
    int nodeBase = b << BSH;
    for (int i = tid; i < BNODES; i += 256) cur[i] = 0;
    __syncthreads();
    int cnt = gcur[b];
    if (cnt > CAP) cnt = CAP;
    const unsigned* bp = bkt + (size_t)b * CAP;
    for (int k = tid; k < cnt; k += 256) {
        unsigned p = bp[k];                // L2-resident
        int ld = p & (BNODES - 1);
        int r = atomicAdd(&cur[ld], 1);
        if (r < MAXDEG) rows[ld][r] = (int)(p >> BSH);
    }
    __syncthreads();

    float4 c = *consts;
    int lane = tid & 63, w = tid >> 6;
    float w1a = W1[2 * lane], w1b = W1[2 * lane + 1], b1j = b1[lane];
    float w2a = W2[lane], w2b = W2[64 + lane];
    float sa = as2[0], sb = as2[1], da = ad2[0], db = ad2[1];
    #pragma unroll 4
    for (int t = 0; t < 32; ++t) {
        int i = (w << 5) + t;              // wave w owns nodes w*32..+31
        int n = nodeBase + i;
        if (n >= N) break;                 // wave-uniform
        int dg = cur[i];
        if (dg > MAXDEG) dg = MAXDEG;
        float2 xn = x[n];
        float adst_n = fmaf(xn.x, c.z, xn.y * c.w);
        float sp = 0.f, s0 = 0.f, s1 = 0.f;
        if (lane < dg) {
            int s = rows[i][lane];
            float2 xs = x[s];              // 8B gather, L1/L2-resident
            float e = lrelu(fmaf(xs.x, c.x, xs.y * c.y) + adst_n);
            float pv = __expf(e);          // unshifted; softmax shift-invariant
            sp = pv;
            s0 = pv * xs.x;
            s1 = pv * xs.y;
        }
        sp = wave_sum(sp);
        s0 = wave_sum(s0);
        s1 = wave_sum(s1);
        float rden = 1.f / (sp + EPS);
        float a = fmaf(w1a, s0, w1b * s1) * rden;
        float hr = fmaxf(a + b1j, 0.f);
        float q0 = wave_sum(hr * w2a);
        float q1 = wave_sum(hr * w2b);
        if (lane == 0)
            pack2[n] = make_float4(q0, q1,
                                   fmaf(q0, sa, q1 * sb),
                                   fmaf(q0, da, q1 * db));
    }
}

// ====== fused distrib + layer-2 agg + bias + log_softmax ======
__global__ __launch_bounds__(256)
void agg2f_kernel(const int* __restrict__ gcur, const unsigned* __restrict__ bkt,
                  const float4* __restrict__ pack2, const float* __restrict__ b2,
                  float2* __restrict__ out, int N) {
    __shared__ int rows[BNODES][MAXDEG];   // 32 KB
    __shared__ int cur[BNODES];
    int b = blockIdx.x, tid = threadIdx.x;
    int nodeBase = b << BSH;
    for (int i = tid; i < BNODES; i += 256) cur[i] = 0;
    __syncthreads();
    int cnt = gcur[b];
    if (cnt > CAP) cnt = CAP;
    const unsigned* bp = bkt + (size_t)b * CAP;
    for (int k = tid; k < cnt; k += 256) {
        unsigned p = bp[k];
        int ld = p & (BNODES - 1);
        int r = atomicAdd(&cur[ld], 1);
        if (r < MAXDEG) rows[ld][r] = (int)(p >> BSH);
    }
    __syncthreads();

    int lane = tid & 63, w = tid >> 6;
    float B0 = b2[0], B1 = b2[1];
    #pragma unroll 4
    for (int t = 0; t < 32; ++t) {
        int i = (w << 5) + t;
        int n = nodeBase + i;
        if (n >= N) break;                 // wave-uniform
        int dg = cur[i];
        if (dg > MAXDEG) dg = MAXDEG;
        float adst_n = ((const float*)(pack2 + n))[3];   // broadcast load
        float sp = 0.f, a0 = 0.f, a1 = 0.f;
        if (lane < dg) {
            int s = rows[i][lane];
            float4 P = pack2[s];           // 16B gather, L2-resident
            float pv = __expf(lrelu(P.z + adst_n));
            sp = pv;
            a0 = pv * P.x;
            a1 = pv * P.y;
        }
        sp = wave_sum(sp);
        a0 = wave_sum(a0);
        a1 = wave_sum(a1);
        if (lane == 0) {
            float rd = 1.f / (sp + EPS);
            float v0 = fmaf(a0, rd, B0);
            float v1 = fmaf(a1, rd, B1);
            float mx = fmaxf(v0, v1);
            float lse = mx + logf(__expf(v0 - mx) + __expf(v1 - mx));
            out[n] = make_float2(v0 - lse, v1 - lse);
        }
    }
}

extern "C" void kernel_launch(void* const* d_in, const int* in_sizes, int n_in,
                              void* d_out, int out_size, void* d_ws, size_t ws_size,
                              hipStream_t stream) {
    const float* x      = (const float*)d_in[0];
    const int*   eidx   = (const int*)d_in[1];
    const float* W1     = (const float*)d_in[2];
    const float* att_s1 = (const float*)d_in[3];
    const float* att_d1 = (const float*)d_in[4];
    const float* b1     = (const float*)d_in[5];
    const float* W2     = (const float*)d_in[6];
    const float* att_s2 = (const float*)d_in[7];
    const float* att_d2 = (const float*)d_in[8];
    const float* b2     = (const float*)d_in[9];

    const int N     = in_sizes[0] / 2;   // x is [N,2]
    const int E     = in_sizes[1] / 2;   // edge_index is [2,E]
    const int Etot  = E + N;             // + self loops
    const int nbuck = (N + BNODES - 1) >> BSH;   // 782 for N=100k (<= NBMAX)

    const int* src = eidx;
    const int* dst = eidx + E;

    // ---- workspace carve-up (16B aligned) ----
    char* w = (char*)(((uintptr_t)d_ws + 15) & ~(uintptr_t)15);
    int*      gcur   = (int*)w;      w += (size_t)NBMAX * 4;
    unsigned* bkt    = (unsigned*)w; w += (size_t)nbuck * CAP * 4;
    float4*   pack2  = (float4*)w;   w += (size_t)N * 16;
    float4*   consts = (float4*)w;   w += 16;

    const int B = 256;
    dim3 blk(B);

    // consts + gcur zeroing
    const_kernel<<<dim3(1), dim3(1024), 0, stream>>>(W1, att_s1, att_d1, consts, gcur);

    // ---- pass 1: bucket partition ----
    int nblocks = (Etot + B * EPT - 1) / (B * EPT);
    bucket_kernel<<<dim3(nblocks), blk, 0, stream>>>(src, dst, gcur, bkt, E, Etot, nbuck);

    // ---- fused distrib + layer-1 agg + node2 ----
    agg1f_kernel<<<dim3(nbuck), blk, 0, stream>>>(
        gcur, bkt, (const float2*)x, consts, W1, b1, W2, att_s2, att_d2, pack2, N);

    // ---- fused distrib + layer-2 agg + bias + log_softmax ----
    agg2f_kernel<<<dim3(nbuck), blk, 0, stream>>>(
        gcur, bkt, pack2, b2, (float2*)d_out, N);
}

// Round 14
// 88.238 us; speedup vs baseline: 1.3218x; 1.3218x over previous
//
#include <hip/hip_runtime.h>
#include <cstdint>

#define NEG_SLOPE 0.2f
#define EPS 1e-16f
#define BSH 7                  // 128 nodes per bucket
#define BNODES (1 << BSH)
#define NBMAX 1024             // supports N <= 131072
#define CAP 2560               // bucket capacity (mean ~1766, +19 sigma)
#define EPT 16                 // edges per thread in bucket pass
#define MAXDEG 64              // padded CSR row (Poisson(12.8)+self-loop << 64)

__device__ __forceinline__ float lrelu(float x) {
    return (x >= 0.f) ? x : NEG_SLOPE * x;
}

// ---- wave-wide sum, DPP rotate-reduce ----
// 4 row_ror stages (VALU pipe, 16-lane rows) + 2 shfl_xor stages (LDS pipe)
// instead of 6 shfl_xor stages: LDS-pipe ops per reduction 6 -> 2. All-lane
// broadcast result. Requires full EXEC (callers' divergence is wave-uniform:
// n = gid>>6 is identical across the wave). dpp_ctrl must be a compile-time
// constant -> template parameter (round-13 compile fix).
template <int CTRL>
__device__ __forceinline__ float dpp_ror_add(float v) {
    int r = __builtin_amdgcn_update_dpp(0, __float_as_int(v), CTRL, 0xf, 0xf, true);
    return v + __int_as_float(r);
}
__device__ __forceinline__ float wave_sum(float v) {
    v = dpp_ror_add<0x121>(v);   // row_ror:1
    v = dpp_ror_add<0x122>(v);   // row_ror:2
    v = dpp_ror_add<0x124>(v);   // row_ror:4
    v = dpp_ror_add<0x128>(v);   // row_ror:8  -> full 16-lane row sum
    v += __shfl_xor(v, 16);
    v += __shfl_xor(v, 32);
    return v;
}

// ---- consts + gcur zeroing (rocclr fill kernel costs ~40us/replay) ----
// wave 0: {c0,c1} = W1^T att_s1, {d0,d1} = W1^T att_d1.
__global__ __launch_bounds__(1024)
void const_kernel(const float* __restrict__ W1,
                  const float* __restrict__ as1,
                  const float* __restrict__ ad1,
                  float4* __restrict__ consts,
                  int* __restrict__ gcur) {
    int tid = threadIdx.x;
    gcur[tid] = 0;                       // NBMAX == 1024
    if (tid < 64) {
        float w0 = W1[2 * tid], w1 = W1[2 * tid + 1];
        float s = as1[tid], d = ad1[tid];
        float c0 = wave_sum(w0 * s);
        float c1 = wave_sum(w1 * s);
        float e0 = wave_sum(w0 * d);
        float e1 = wave_sum(w1 * d);
        if (tid == 0) *consts = make_float4(c0, c1, e0, e1);
    }
}

// ---- pass 1: bucket partition by dst>>7, two-read-pass, cached chunked
// stores (L2-merged; NT stores paid 32B/edge — round-9 lesson).
__global__ __launch_bounds__(256)
void bucket_kernel(const int* __restrict__ src, const int* __restrict__ dst,
                   int* __restrict__ gcur, unsigned* __restrict__ bkt,
                   int E, int Etot, int nbuck) {
    __shared__ int cnt[NBMAX];
    __shared__ int base[NBMAX];
    int tid = threadIdx.x;
    int blockBase = blockIdx.x * (256 * EPT);
    for (int b = tid; b < nbuck; b += 256) cnt[b] = 0;
    __syncthreads();

    #pragma unroll
    for (int k = 0; k < EPT; ++k) {
        int i = blockBase + k * 256 + tid;
        if (i < Etot) {
            int d = (i < E) ? dst[i] : (i - E);
            atomicAdd(&cnt[d >> BSH], 1);
        }
    }
    __syncthreads();
    for (int b = tid; b < nbuck; b += 256) {
        int c = cnt[b];
        base[b] = c ? atomicAdd(gcur + b, c) : 0;
    }
    __syncthreads();
    for (int b = tid; b < nbuck; b += 256) cnt[b] = 0;
    __syncthreads();

    #pragma unroll
    for (int k = 0; k < EPT; ++k) {
        int i = blockBase + k * 256 + tid;
        if (i < Etot) {
            int s, d;
            if (i < E) { s = src[i]; d = dst[i]; } else { s = d = i - E; }
            int b = d >> BSH;
            unsigned p = ((unsigned)s << BSH) | (unsigned)(d & (BNODES - 1));
            int pos = base[b] + atomicAdd(&cnt[b], 1);
            if (pos < CAP) bkt[(size_t)b * CAP + pos] = p;   // cached store
        }
    }
}

// ---- pass 2: distribute bucket payload into padded per-node CSR rows ----
// one block per bucket; all csr writes land in this bucket's 32KB window
// (L2-merged). Cursors are LDS ints.
__global__ __launch_bounds__(256)
void distrib_kernel(const int* __restrict__ gcur, const unsigned* __restrict__ bkt,
                    int* __restrict__ csr, int* __restrict__ deg, int N) {
    __shared__ int cur[BNODES];
    int b = blockIdx.x, tid = threadIdx.x;
    int nodeBase = b << BSH;
    for (int i = tid; i < BNODES; i += 256) cur[i] = 0;
    __syncthreads();
    int cnt = gcur[b];
    if (cnt > CAP) cnt = CAP;
    const unsigned* bp = bkt + (size_t)b * CAP;
    for (int k = tid; k < cnt; k += 256) {
        unsigned p = bp[k];
        int ld = p & (BNODES - 1);
        int s = p >> BSH;
        int r = atomicAdd(&cur[ld], 1);
        if (r < MAXDEG)
            csr[((size_t)(nodeBase + ld) << 6) + r] = s;
    }
    __syncthreads();
    for (int i = tid; i < BNODES; i += 256) {
        int n = nodeBase + i;
        if (n < N) deg[n] = (cur[i] < MAXDEG) ? cur[i] : MAXDEG;
    }
}

// ====== layer-1 agg: wave per node, atomic-free + fused node2 ======
// lane = CSR slot (deg <= 64 -> no loop); epilogue reuses lane as feature j.
__global__ __launch_bounds__(256)
void agg1_kernel(const int* __restrict__ deg, const int* __restrict__ csr,
                 const float2* __restrict__ x, const float4* __restrict__ consts,
                 const float* __restrict__ W1, const float* __restrict__ b1,
                 const float* __restrict__ W2, const float* __restrict__ as2,
                 const float* __restrict__ ad2, float4* __restrict__ pack2,
                 int N) {
    int gid = blockIdx.x * blockDim.x + threadIdx.x;
    int n = gid >> 6, lane = gid & 63;
    if (n >= N) return;
    int dg = deg[n];
    float4 c = *consts;
    float2 xn = x[n];
    float adst_n = fmaf(xn.x, c.z, xn.y * c.w);

    float sp = 0.f, s0 = 0.f, s1 = 0.f;
    if (lane < dg) {
        int s = csr[((size_t)n << 6) + lane];   // coalesced, exec-masked
        float2 xs = x[s];                       // 8B gather, L2-resident
        float e = lrelu(fmaf(xs.x, c.x, xs.y * c.y) + adst_n);
        float pv = __expf(e);   // unshifted: |e| small; softmax shift-invariant
        sp = pv;
        s0 = pv * xs.x;
        s1 = pv * xs.y;
    }
    sp = wave_sum(sp);
    s0 = wave_sum(s0);
    s1 = wave_sum(s1);
    float rden = 1.f / (sp + EPS);

    // node2 epilogue: lane j = hidden feature j
    float a = fmaf(W1[2 * lane], s0, W1[2 * lane + 1] * s1) * rden;
    float hr = fmaxf(a + b1[lane], 0.f);
    float q0 = wave_sum(hr * W2[lane]);
    float q1 = wave_sum(hr * W2[64 + lane]);
    if (lane == 0)
        pack2[n] = make_float4(q0, q1,
                               fmaf(q0, as2[0], q1 * as2[1]),
                               fmaf(q0, ad2[0], q1 * ad2[1]));
}

// ====== layer-2 agg: wave per node + bias + log_softmax ======
__global__ __launch_bounds__(256)
void agg2_kernel(const int* __restrict__ deg, const int* __restrict__ csr,
                 const float4* __restrict__ pack2, const float* __restrict__ b2,
                 float2* __restrict__ out, int N) {
    int gid = blockIdx.x * blockDim.x + threadIdx.x;
    int n = gid >> 6, lane = gid & 63;
    if (n >= N) return;
    int dg = deg[n];
    float adst_n = ((const float*)(pack2 + n))[3];

    float sp = 0.f, a0 = 0.f, a1 = 0.f;
    if (lane < dg) {
        int s = csr[((size_t)n << 6) + lane];
        float4 P = pack2[s];                    // 16B gather, L2-resident
        float pv = __expf(lrelu(P.z + adst_n));
        sp = pv;
        a0 = pv * P.x;
        a1 = pv * P.y;
    }
    sp = wave_sum(sp);
    a0 = wave_sum(a0);
    a1 = wave_sum(a1);

    if (lane == 0) {
        float rd = 1.f / (sp + EPS);
        float v0 = fmaf(a0, rd, b2[0]);
        float v1 = fmaf(a1, rd, b2[1]);
        float mx = fmaxf(v0, v1);
        float lse = mx + logf(__expf(v0 - mx) + __expf(v1 - mx));
        out[n] = make_float2(v0 - lse, v1 - lse);
    }
}

extern "C" void kernel_launch(void* const* d_in, const int* in_sizes, int n_in,
                              void* d_out, int out_size, void* d_ws, size_t ws_size,
                              hipStream_t stream) {
    const float* x      = (const float*)d_in[0];
    const int*   eidx   = (const int*)d_in[1];
    const float* W1     = (const float*)d_in[2];
    const float* att_s1 = (const float*)d_in[3];
    const float* att_d1 = (const float*)d_in[4];
    const float* b1     = (const float*)d_in[5];
    const float* W2     = (const float*)d_in[6];
    const float* att_s2 = (const float*)d_in[7];
    const float* att_d2 = (const float*)d_in[8];
    const float* b2     = (const float*)d_in[9];

    const int N     = in_sizes[0] / 2;   // x is [N,2]
    const int E     = in_sizes[1] / 2;   // edge_index is [2,E]
    const int Etot  = E + N;             // + self loops
    const int nbuck = (N + BNODES - 1) >> BSH;   // 782 for N=100k (<= NBMAX)

    const int* src = eidx;
    const int* dst = eidx + E;

    // ---- workspace carve-up (16B aligned) ----
    char* w = (char*)(((uintptr_t)d_ws + 15) & ~(uintptr_t)15);
    int*      gcur   = (int*)w;      w += (size_t)NBMAX * 4;
    unsigned* bkt    = (unsigned*)w; w += (size_t)nbuck * CAP * 4;
    int*      csr    = (int*)w;      w += (size_t)N * MAXDEG * 4;
    int*      deg    = (int*)w;      w += (size_t)N * 4;
    float4*   pack2  = (float4*)w;   w += (size_t)N * 16;
    float4*   consts = (float4*)w;   w += 16;

    const int B = 256;
    dim3 blk(B);

    // consts + gcur zeroing (no hipMemsetAsync: rocclr fill = 40us/replay)
    const_kernel<<<dim3(1), dim3(1024), 0, stream>>>(W1, att_s1, att_d1, consts, gcur);

    // ---- pass 1: bucket partition (two-read-pass, merged cached stores) ----
    int nblocks = (Etot + B * EPT - 1) / (B * EPT);
    bucket_kernel<<<dim3(nblocks), blk, 0, stream>>>(src, dst, gcur, bkt, E, Etot, nbuck);

    // ---- pass 2: bucket payload -> padded per-node CSR (L2-local scatter) ----
    distrib_kernel<<<dim3(nbuck), blk, 0, stream>>>(gcur, bkt, csr, deg, N);

    // ---- layer-1 agg (wave per node, atomic-free) + fused node2 ----
    agg1_kernel<<<dim3((unsigned)(((long long)N * 64 + B - 1) / B)), blk, 0, stream>>>(
        deg, csr, (const float2*)x, consts, W1, b1, W2, att_s2, att_d2, pack2, N);

    // ---- layer-2 agg + bias + log_softmax ----
    agg2_kernel<<<dim3((unsigned)(((long long)N * 64 + B - 1) / B)), blk, 0, stream>>>(
        deg, csr, pack2, b2, (float2*)d_out, N);
}

// Round 15
// 76.682 us; speedup vs baseline: 1.5210x; 1.1507x over previous
//
#include <hip/hip_runtime.h>
#include <cstdint>

#define NEG_SLOPE 0.2f
#define EPS 1e-16f
#define BSH 7                  // 128 nodes per bucket
#define BNODES (1 << BSH)
#define NBMAX 1024             // supports N <= 131072
#define CAP 2560               // bucket capacity (mean ~1766, +19 sigma)
#define EPT 16                 // edges per thread in bucket pass
#define MAXDEG 64              // padded row (Poisson(12.8)+self-loop << 64)
#define AGG_T 1024             // 16 waves per agg block (round-12 fix #1)

__device__ __forceinline__ float lrelu(float x) {
    return (x >= 0.f) ? x : NEG_SLOPE * x;
}

// ---- wave-wide sum, DPP rotate-reduce (round-14 win) ----
// 4 row_ror stages (VALU pipe) + 2 shfl_xor (LDS pipe). Full-exec callers.
template <int CTRL>
__device__ __forceinline__ float dpp_ror_add(float v) {
    int r = __builtin_amdgcn_update_dpp(0, __float_as_int(v), CTRL, 0xf, 0xf, true);
    return v + __int_as_float(r);
}
__device__ __forceinline__ float wave_sum(float v) {
    v = dpp_ror_add<0x121>(v);   // row_ror:1
    v = dpp_ror_add<0x122>(v);   // row_ror:2
    v = dpp_ror_add<0x124>(v);   // row_ror:4
    v = dpp_ror_add<0x128>(v);   // row_ror:8
    v += __shfl_xor(v, 16);
    v += __shfl_xor(v, 32);
    return v;
}

// ---- consts + gcur zeroing (rocclr fill kernel is expensive in-graph) ----
__global__ __launch_bounds__(1024)
void const_kernel(const float* __restrict__ W1,
                  const float* __restrict__ as1,
                  const float* __restrict__ ad1,
                  float4* __restrict__ consts,
                  int* __restrict__ gcur) {
    int tid = threadIdx.x;
    gcur[tid] = 0;                       // NBMAX == 1024
    if (tid < 64) {
        float w0 = W1[2 * tid], w1 = W1[2 * tid + 1];
        float s = as1[tid], d = ad1[tid];
        float c0 = wave_sum(w0 * s);
        float c1 = wave_sum(w1 * s);
        float e0 = wave_sum(w0 * d);
        float e1 = wave_sum(w1 * d);
        if (tid == 0) *consts = make_float4(c0, c1, e0, e1);
    }
}

// ---- pass 1: bucket partition by dst>>7, two-read-pass, cached chunked
// stores (L2-merged; NT stores paid 32B/edge — round-9 lesson).
__global__ __launch_bounds__(256)
void bucket_kernel(const int* __restrict__ src, const int* __restrict__ dst,
                   int* __restrict__ gcur, unsigned* __restrict__ bkt,
                   int E, int Etot, int nbuck) {
    __shared__ int cnt[NBMAX];
    __shared__ int base[NBMAX];
    int tid = threadIdx.x;
    int blockBase = blockIdx.x * (256 * EPT);
    for (int b = tid; b < nbuck; b += 256) cnt[b] = 0;
    __syncthreads();

    #pragma unroll
    for (int k = 0; k < EPT; ++k) {
        int i = blockBase + k * 256 + tid;
        if (i < Etot) {
            int d = (i < E) ? dst[i] : (i - E);
            atomicAdd(&cnt[d >> BSH], 1);
        }
    }
    __syncthreads();
    for (int b = tid; b < nbuck; b += 256) {
        int c = cnt[b];
        base[b] = c ? atomicAdd(gcur + b, c) : 0;
    }
    __syncthreads();
    for (int b = tid; b < nbuck; b += 256) cnt[b] = 0;
    __syncthreads();

    #pragma unroll
    for (int k = 0; k < EPT; ++k) {
        int i = blockBase + k * 256 + tid;
        if (i < Etot) {
            int s, d;
            if (i < E) { s = src[i]; d = dst[i]; } else { s = d = i - E; }
            int b = d >> BSH;
            unsigned p = ((unsigned)s << BSH) | (unsigned)(d & (BNODES - 1));
            int pos = base[b] + atomicAdd(&cnt[b], 1);
            if (pos < CAP) bkt[(size_t)b * CAP + pos] = p;   // cached store
        }
    }
}

// ====== fused distrib + layer-1 agg + node2: one 1024-thr block/bucket ====
// Build 128 padded rows in LDS, then 16 waves × 8 nodes each, wave-per-node
// with lane = slot; DPP reductions; node2 epilogue reuses lane as feature j.
__global__ __launch_bounds__(AGG_T)
void agg1f_kernel(const int* __restrict__ gcur, const unsigned* __restrict__ bkt,
                  const float2* __restrict__ x, const float4* __restrict__ consts,
                  const float* __restrict__ W1, const float* __restrict__ b1,
                  const float* __restrict__ W2, const float* __restrict__ as2,
                  const float* __restrict__ ad2, float4* __restrict__ pack2,
                  int N) {
    __shared__ int rows[BNODES][MAXDEG];   // 32 KB
    __shared__ int cur[BNODES];
    int b = blockIdx.x, tid = threadIdx.x;
    int nodeBase = b << BSH;
    if (tid < BNODES) cur[tid] = 0;
    __syncthreads();
    int cnt = gcur[b];
    if (cnt > CAP) cnt = CAP;
    const unsigned* bp = bkt + (size_t)b * CAP;
    for (int k = tid; k < cnt; k += AGG_T) {
        unsigned p = bp[k];                // L2-resident payload
        int ld = p & (BNODES - 1);
        int r = atomicAdd(&cur[ld], 1);
        if (r < MAXDEG) rows[ld][r] = (int)(p >> BSH);
    }
    __syncthreads();

    float4 c = *consts;
    int lane = tid & 63, w = tid >> 6;     // 16 waves
    float w1a = W1[2 * lane], w1b = W1[2 * lane + 1], b1j = b1[lane];
    float w2a = W2[lane], w2b = W2[64 + lane];
    float sa = as2[0], sb = as2[1], da = ad2[0], db = ad2[1];
    #pragma unroll 2
    for (int t = 0; t < 8; ++t) {
        int i = (w << 3) + t;              // wave w owns nodes w*8..w*8+7
        int n = nodeBase + i;
        if (n >= N) break;                 // wave-uniform
        int dg = cur[i];
        if (dg > MAXDEG) dg = MAXDEG;
        float2 xn = x[n];
        float adst_n = fmaf(xn.x, c.z, xn.y * c.w);
        float sp = 0.f, s0 = 0.f, s1 = 0.f;
        if (lane < dg) {
            int s = rows[i][lane];         // 2-way bank alias = free
            float2 xs = x[s];              // 8B gather, L2-resident
            float e = lrelu(fmaf(xs.x, c.x, xs.y * c.y) + adst_n);
            float pv = __expf(e);          // unshifted; softmax shift-invariant
            sp = pv;
            s0 = pv * xs.x;
            s1 = pv * xs.y;
        }
        sp = wave_sum(sp);
        s0 = wave_sum(s0);
        s1 = wave_sum(s1);
        float rden = 1.f / (sp + EPS);
        float a = fmaf(w1a, s0, w1b * s1) * rden;
        float hr = fmaxf(a + b1j, 0.f);
        float q0 = wave_sum(hr * w2a);
        float q1 = wave_sum(hr * w2b);
        if (lane == 0)
            pack2[n] = make_float4(q0, q1,
                                   fmaf(q0, sa, q1 * sb),
                                   fmaf(q0, da, q1 * db));
    }
}

// ====== fused distrib + layer-2 agg + bias + log_softmax ======
__global__ __launch_bounds__(AGG_T)
void agg2f_kernel(const int* __restrict__ gcur, const unsigned* __restrict__ bkt,
                  const float4* __restrict__ pack2, const float* __restrict__ b2,
                  float2* __restrict__ out, int N) {
    __shared__ int rows[BNODES][MAXDEG];   // 32 KB
    __shared__ int cur[BNODES];
    int b = blockIdx.x, tid = threadIdx.x;
    int nodeBase = b << BSH;
    if (tid < BNODES) cur[tid] = 0;
    __syncthreads();
    int cnt = gcur[b];
    if (cnt > CAP) cnt = CAP;
    const unsigned* bp = bkt + (size_t)b * CAP;
    for (int k = tid; k < cnt; k += AGG_T) {
        unsigned p = bp[k];
        int ld = p & (BNODES - 1);
        int r = atomicAdd(&cur[ld], 1);
        if (r < MAXDEG) rows[ld][r] = (int)(p >> BSH);
    }
    __syncthreads();

    int lane = tid & 63, w = tid >> 6;
    float B0 = b2[0], B1 = b2[1];
    #pragma unroll 2
    for (int t = 0; t < 8; ++t) {
        int i = (w << 3) + t;
        int n = nodeBase + i;
        if (n >= N) break;                 // wave-uniform
        int dg = cur[i];
        if (dg > MAXDEG) dg = MAXDEG;
        float adst_n = ((const float*)(pack2 + n))[3];
        float sp = 0.f, a0 = 0.f, a1 = 0.f;
        if (lane < dg) {
            int s = rows[i][lane];
            float4 P = pack2[s];           // 16B gather, L2-resident
            float pv = __expf(lrelu(P.z + adst_n));
            sp = pv;
            a0 = pv * P.x;
            a1 = pv * P.y;
        }
        sp = wave_sum(sp);
        a0 = wave_sum(a0);
        a1 = wave_sum(a1);
        if (lane == 0) {
            float rd = 1.f / (sp + EPS);
            float v0 = fmaf(a0, rd, B0);
            float v1 = fmaf(a1, rd, B1);
            float mx = fmaxf(v0, v1);
            float lse = mx + logf(__expf(v0 - mx) + __expf(v1 - mx));
            out[n] = make_float2(v0 - lse, v1 - lse);
        }
    }
}

extern "C" void kernel_launch(void* const* d_in, const int* in_sizes, int n_in,
                              void* d_out, int out_size, void* d_ws, size_t ws_size,
                              hipStream_t stream) {
    const float* x      = (const float*)d_in[0];
    const int*   eidx   = (const int*)d_in[1];
    const float* W1     = (const float*)d_in[2];
    const float* att_s1 = (const float*)d_in[3];
    const float* att_d1 = (const float*)d_in[4];
    const float* b1     = (const float*)d_in[5];
    const float* W2     = (const float*)d_in[6];
    const float* att_s2 = (const float*)d_in[7];
    const float* att_d2 = (const float*)d_in[8];
    const float* b2     = (const float*)d_in[9];

    const int N     = in_sizes[0] / 2;   // x is [N,2]
    const int E     = in_sizes[1] / 2;   // edge_index is [2,E]
    const int Etot  = E + N;             // + self loops
    const int nbuck = (N + BNODES - 1) >> BSH;   // 782 for N=100k (<= NBMAX)

    const int* src = eidx;
    const int* dst = eidx + E;

    // ---- workspace carve-up (16B aligned) ----
    char* w = (char*)(((uintptr_t)d_ws + 15) & ~(uintptr_t)15);
    int*      gcur   = (int*)w;      w += (size_t)NBMAX * 4;
    unsigned* bkt    = (unsigned*)w; w += (size_t)nbuck * CAP * 4;
    float4*   pack2  = (float4*)w;   w += (size_t)N * 16;
    float4*   consts = (float4*)w;   w += 16;

    const int B = 256;

    // consts + gcur zeroing
    const_kernel<<<dim3(1), dim3(1024), 0, stream>>>(W1, att_s1, att_d1, consts, gcur);

    // ---- pass 1: bucket partition ----
    int nblocks = (Etot + B * EPT - 1) / (B * EPT);
    bucket_kernel<<<dim3(nblocks), dim3(B), 0, stream>>>(src, dst, gcur, bkt, E, Etot, nbuck);

    // ---- fused distrib + layer-1 agg + node2 (16 waves/block) ----
    agg1f_kernel<<<dim3(nbuck), dim3(AGG_T), 0, stream>>>(
        gcur, bkt, (const float2*)x, consts, W1, b1, W2, att_s2, att_d2, pack2, N);

    // ---- fused distrib + layer-2 agg + bias + log_softmax ----
    agg2f_kernel<<<dim3(nbuck), dim3(AGG_T), 0, stream>>>(
        gcur, bkt, pack2, b2, (float2*)d_out, N);
}

// Round 16
// 65.539 us; speedup vs baseline: 1.7795x; 1.1700x over previous
//
#include <hip/hip_runtime.h>
#include <cstdint>

#define NEG_SLOPE 0.2f
#define EPS 1e-16f
#define BSH 7                  // 128 nodes per bucket
#define BNODES (1 << BSH)
#define NBMAX 1024             // supports N <= 131072
#define CAP 2560               // bucket capacity (mean ~1766, +19 sigma)
#define EPT 32                 // edges per thread in bucket pass
#define MAXDEG 64              // padded row (Poisson(12.8)+self-loop << 64)
#define ROWP 65                // row stride: (i*65+r)%32 distinct per lane

__device__ __forceinline__ float lrelu(float x) {
    return (x >= 0.f) ? x : NEG_SLOPE * x;
}

// ---- wave-wide sum (const_kernel only), DPP rotate-reduce ----
template <int CTRL>
__device__ __forceinline__ float dpp_ror_add(float v) {
    int r = __builtin_amdgcn_update_dpp(0, __float_as_int(v), CTRL, 0xf, 0xf, true);
    return v + __int_as_float(r);
}
__device__ __forceinline__ float wave_sum(float v) {
    v = dpp_ror_add<0x121>(v);
    v = dpp_ror_add<0x122>(v);
    v = dpp_ror_add<0x124>(v);
    v = dpp_ror_add<0x128>(v);
    v += __shfl_xor(v, 16);
    v += __shfl_xor(v, 32);
    return v;
}

// ---- consts + gcur zeroing (rocclr fill is expensive in-graph) ----
__global__ __launch_bounds__(1024)
void const_kernel(const float* __restrict__ W1,
                  const float* __restrict__ as1,
                  const float* __restrict__ ad1,
                  float4* __restrict__ consts,
                  int* __restrict__ gcur) {
    int tid = threadIdx.x;
    gcur[tid] = 0;                       // NBMAX == 1024
    if (tid < 64) {
        float w0 = W1[2 * tid], w1 = W1[2 * tid + 1];
        float s = as1[tid], d = ad1[tid];
        float c0 = wave_sum(w0 * s);
        float c1 = wave_sum(w1 * s);
        float e0 = wave_sum(w0 * d);
        float e1 = wave_sum(w1 * d);
        if (tid == 0) *consts = make_float4(c0, c1, e0, e1);
    }
}

// ---- pass 1: bucket partition by dst>>7, two-read-pass, cached chunked
// stores (L2-merged). EPT=32: fewer blocks -> half the global atomics.
__global__ __launch_bounds__(256)
void bucket_kernel(const int* __restrict__ src, const int* __restrict__ dst,
                   int* __restrict__ gcur, unsigned* __restrict__ bkt,
                   int E, int Etot, int nbuck) {
    __shared__ int cnt[NBMAX];
    __shared__ int base[NBMAX];
    int tid = threadIdx.x;
    int blockBase = blockIdx.x * (256 * EPT);
    for (int b = tid; b < nbuck; b += 256) cnt[b] = 0;
    __syncthreads();

    #pragma unroll
    for (int k = 0; k < EPT; ++k) {
        int i = blockBase + k * 256 + tid;
        if (i < Etot) {
            int d = (i < E) ? dst[i] : (i - E);
            atomicAdd(&cnt[d >> BSH], 1);
        }
    }
    __syncthreads();
    for (int b = tid; b < nbuck; b += 256) {
        int c = cnt[b];
        base[b] = c ? atomicAdd(gcur + b, c) : 0;
    }
    __syncthreads();
    for (int b = tid; b < nbuck; b += 256) cnt[b] = 0;
    __syncthreads();

    #pragma unroll
    for (int k = 0; k < EPT; ++k) {
        int i = blockBase + k * 256 + tid;
        if (i < Etot) {
            int s, d;
            if (i < E) { s = src[i]; d = dst[i]; } else { s = d = i - E; }
            int b = d >> BSH;
            unsigned p = ((unsigned)s << BSH) | (unsigned)(d & (BNODES - 1));
            int pos = base[b] + atomicAdd(&cnt[b], 1);
            if (pos < CAP) bkt[(size_t)b * CAP + pos] = p;   // cached store
        }
    }
}

// ====== fused distrib + layer-1 agg + node2, LANE-PER-NODE ======
// 128 threads/block, one block per bucket. Build padded rows in LDS, then
// lane owns node (wave*64+lane): serial edge loop in registers, then serial
// 64-feature epilogue over an LDS weight table. No cross-lane ops at all.
__global__ __launch_bounds__(128)
void agg1t_kernel(const int* __restrict__ gcur, const unsigned* __restrict__ bkt,
                  const float2* __restrict__ x, const float4* __restrict__ consts,
                  const float* __restrict__ W1, const float* __restrict__ b1,
                  const float* __restrict__ W2, const float* __restrict__ as2,
                  const float* __restrict__ ad2, float4* __restrict__ pack2,
                  int N) {
    __shared__ int rows[BNODES * ROWP];    // 33.3 KB
    __shared__ int cur[BNODES];
    __shared__ float4 tab[64];             // {w1a, w1b, b1, w2a}
    __shared__ float w2bL[64];
    int b = blockIdx.x, tid = threadIdx.x;
    int nodeBase = b << BSH;
    cur[tid] = 0;
    if (tid < 64) {
        tab[tid] = make_float4(W1[2 * tid], W1[2 * tid + 1], b1[tid], W2[tid]);
        w2bL[tid] = W2[64 + tid];
    }
    __syncthreads();

    int cnt = gcur[b];
    if (cnt > CAP) cnt = CAP;
    const unsigned* bp = bkt + (size_t)b * CAP;
    for (int k = tid; k < cnt; k += 128) {
        unsigned p = bp[k];                // L2-resident payload
        int ld = p & (BNODES - 1);
        int r = atomicAdd(&cur[ld], 1);
        if (r < MAXDEG) rows[ld * ROWP + r] = (int)(p >> BSH);
    }
    __syncthreads();

    int i = tid;                           // lane-per-node (2 waves cover 128)
    int n = nodeBase + i;
    if (n >= N) return;
    int dg = cur[i];
    if (dg > MAXDEG) dg = MAXDEG;
    float4 c = *consts;
    float2 xn = x[n];                      // coalesced 8B
    float adst_n = fmaf(xn.x, c.z, xn.y * c.w);

    float sp = 0.f, s0 = 0.f, s1 = 0.f;
    for (int r = 0; r < dg; ++r) {
        int s = rows[i * ROWP + r];        // conflict-free (stride 65)
        float2 xs = x[s];                  // 8B gather, L2-resident
        float e = lrelu(fmaf(xs.x, c.x, xs.y * c.y) + adst_n);
        float pv = __expf(e);              // unshifted; softmax shift-invariant
        sp += pv;
        s0 = fmaf(pv, xs.x, s0);
        s1 = fmaf(pv, xs.y, s1);
    }
    float rden = 1.f / (sp + EPS);
    s0 *= rden;
    s1 *= rden;

    // node2 epilogue: per-lane serial over 64 features (uniform LDS reads)
    float q0 = 0.f, q1 = 0.f;
    #pragma unroll 8
    for (int j = 0; j < 64; ++j) {
        float4 t = tab[j];
        float hr = fmaxf(fmaf(t.x, s0, t.y * s1) + t.z, 0.f);
        q0 = fmaf(hr, t.w, q0);
        q1 = fmaf(hr, w2bL[j], q1);
    }
    float sa = as2[0], sb = as2[1], da = ad2[0], db = ad2[1];
    pack2[n] = make_float4(q0, q1,
                           fmaf(q0, sa, q1 * sb),
                           fmaf(q0, da, q1 * db));   // coalesced 16B
}

// ====== fused distrib + layer-2 agg + bias + log_softmax, LANE-PER-NODE ====
__global__ __launch_bounds__(128)
void agg2t_kernel(const int* __restrict__ gcur, const unsigned* __restrict__ bkt,
                  const float4* __restrict__ pack2, const float* __restrict__ b2,
                  float2* __restrict__ out, int N) {
    __shared__ int rows[BNODES * ROWP];    // 33.3 KB
    __shared__ int cur[BNODES];
    int b = blockIdx.x, tid = threadIdx.x;
    int nodeBase = b << BSH;
    cur[tid] = 0;
    __syncthreads();

    int cnt = gcur[b];
    if (cnt > CAP) cnt = CAP;
    const unsigned* bp = bkt + (size_t)b * CAP;
    for (int k = tid; k < cnt; k += 128) {
        unsigned p = bp[k];
        int ld = p & (BNODES - 1);
        int r = atomicAdd(&cur[ld], 1);
        if (r < MAXDEG) rows[ld * ROWP + r] = (int)(p >> BSH);
    }
    __syncthreads();

    int i = tid;
    int n = nodeBase + i;
    if (n >= N) return;
    int dg = cur[i];
    if (dg > MAXDEG) dg = MAXDEG;
    float adst_n = ((const float*)(pack2 + n))[3];   // coalesced strided read

    float sp = 0.f, a0 = 0.f, a1 = 0.f;
    for (int r = 0; r < dg; ++r) {
        int s = rows[i * ROWP + r];
        float4 P = pack2[s];               // 16B gather, L2-resident
        float pv = __expf(lrelu(P.z + adst_n));
        sp += pv;
        a0 = fmaf(pv, P.x, a0);
        a1 = fmaf(pv, P.y, a1);
    }
    float rd = 1.f / (sp + EPS);
    float v0 = fmaf(a0, rd, b2[0]);
    float v1 = fmaf(a1, rd, b2[1]);
    float mx = fmaxf(v0, v1);
    float lse = mx + logf(__expf(v0 - mx) + __expf(v1 - mx));
    out[n] = make_float2(v0 - lse, v1 - lse);        // coalesced 8B
}

extern "C" void kernel_launch(void* const* d_in, const int* in_sizes, int n_in,
                              void* d_out, int out_size, void* d_ws, size_t ws_size,
                              hipStream_t stream) {
    const float* x      = (const float*)d_in[0];
    const int*   eidx   = (const int*)d_in[1];
    const float* W1     = (const float*)d_in[2];
    const float* att_s1 = (const float*)d_in[3];
    const float* att_d1 = (const float*)d_in[4];
    const float* b1     = (const float*)d_in[5];
    const float* W2     = (const float*)d_in[6];
    const float* att_s2 = (const float*)d_in[7];
    const float* att_d2 = (const float*)d_in[8];
    const float* b2     = (const float*)d_in[9];

    const int N     = in_sizes[0] / 2;   // x is [N,2]
    const int E     = in_sizes[1] / 2;   // edge_index is [2,E]
    const int Etot  = E + N;             // + self loops
    const int nbuck = (N + BNODES - 1) >> BSH;   // 782 for N=100k (<= NBMAX)

    const int* src = eidx;
    const int* dst = eidx + E;

    // ---- workspace carve-up (16B aligned) ----
    char* w = (char*)(((uintptr_t)d_ws + 15) & ~(uintptr_t)15);
    int*      gcur   = (int*)w;      w += (size_t)NBMAX * 4;
    unsigned* bkt    = (unsigned*)w; w += (size_t)nbuck * CAP * 4;
    float4*   pack2  = (float4*)w;   w += (size_t)N * 16;
    float4*   consts = (float4*)w;   w += 16;

    // consts + gcur zeroing
    const_kernel<<<dim3(1), dim3(1024), 0, stream>>>(W1, att_s1, att_d1, consts, gcur);

    // ---- pass 1: bucket partition ----
    int nblocks = (Etot + 256 * EPT - 1) / (256 * EPT);
    bucket_kernel<<<dim3(nblocks), dim3(256), 0, stream>>>(src, dst, gcur, bkt, E, Etot, nbuck);

    // ---- fused distrib + layer-1 agg + node2 (lane-per-node) ----
    agg1t_kernel<<<dim3(nbuck), dim3(128), 0, stream>>>(
        gcur, bkt, (const float2*)x, consts, W1, b1, W2, att_s2, att_d2, pack2, N);

    // ---- fused distrib + layer-2 agg + bias + log_softmax (lane-per-node) ----
    agg2t_kernel<<<dim3(nbuck), dim3(128), 0, stream>>>(
        gcur, bkt, pack2, b2, (float2*)d_out, N);
}

// Round 17
// 56.000 us; speedup vs baseline: 2.0827x; 1.1703x over previous
//
#include <hip/hip_runtime.h>
#include <cstdint>

#define NEG_SLOPE 0.2f
#define EPS 1e-16f
#define BSH 7                  // 128 nodes per bucket
#define BNODES (1 << BSH)
#define NBMAX 1024             // supports N <= 131072
#define CAP 2560               // bucket capacity (mean ~1766, +19 sigma)
#define MAXDEG 64              // padded row (Poisson(12.8)+self-loop << 64)
#define ROWP 65                // row stride: (i*65+r)%32 distinct per lane
#define BKT_T 1024             // bucket kernel: threads per block
#define BEPT 4                 // bucket kernel: edges per thread

__device__ __forceinline__ float lrelu(float x) {
    return (x >= 0.f) ? x : NEG_SLOPE * x;
}

// ---- wave-wide sum (const_kernel only), DPP rotate-reduce ----
template <int CTRL>
__device__ __forceinline__ float dpp_ror_add(float v) {
    int r = __builtin_amdgcn_update_dpp(0, __float_as_int(v), CTRL, 0xf, 0xf, true);
    return v + __int_as_float(r);
}
__device__ __forceinline__ float wave_sum(float v) {
    v = dpp_ror_add<0x121>(v);
    v = dpp_ror_add<0x122>(v);
    v = dpp_ror_add<0x124>(v);
    v = dpp_ror_add<0x128>(v);
    v += __shfl_xor(v, 16);
    v += __shfl_xor(v, 32);
    return v;
}

// ---- consts + gcur zeroing (rocclr fill is expensive in-graph) ----
__global__ __launch_bounds__(1024)
void const_kernel(const float* __restrict__ W1,
                  const float* __restrict__ as1,
                  const float* __restrict__ ad1,
                  float4* __restrict__ consts,
                  int* __restrict__ gcur) {
    int tid = threadIdx.x;
    gcur[tid] = 0;                       // NBMAX == 1024
    if (tid < 64) {
        float w0 = W1[2 * tid], w1 = W1[2 * tid + 1];
        float s = as1[tid], d = ad1[tid];
        float c0 = wave_sum(w0 * s);
        float c1 = wave_sum(w1 * s);
        float e0 = wave_sum(w0 * d);
        float e1 = wave_sum(w1 * d);
        if (tid == 0) *consts = make_float4(c0, c1, e0, e1);
    }
}

// ---- pass 1: bucket partition by dst>>7 ----
// Round-16 lesson: 169 blocks x 4 waves = wave starvation (occ 5.6%, 42us).
// Now 337 blocks x 16 waves, and pass-1 stages payload+bucket in LDS so
// src/dst are read ONCE (no L2 re-read chain). Chunked cached stores merge
// in L2 (round-9 lesson: NT stores pay 32B/edge).
__global__ __launch_bounds__(BKT_T)
void bucket_kernel(const int* __restrict__ src, const int* __restrict__ dst,
                   int* __restrict__ gcur, unsigned* __restrict__ bkt,
                   int E, int Etot, int nbuck) {
    __shared__ int cnt[NBMAX];                     // 4 KB
    __shared__ int base[NBMAX];                    // 4 KB
    __shared__ unsigned pay[BKT_T * BEPT];         // 16 KB
    __shared__ unsigned short pbk[BKT_T * BEPT];   // 8 KB
    int tid = threadIdx.x;
    int blockBase = blockIdx.x * (BKT_T * BEPT);
    for (int b = tid; b < nbuck; b += BKT_T) cnt[b] = 0;
    __syncthreads();

    // single global read: histogram + stage payload in LDS
    #pragma unroll
    for (int k = 0; k < BEPT; ++k) {
        int idx = k * BKT_T + tid;
        int i = blockBase + idx;
        unsigned p = 0;
        int b = 0;
        bool ok = (i < Etot);
        if (ok) {
            int s, d;
            if (i < E) { s = src[i]; d = dst[i]; } else { s = d = i - E; }
            b = d >> BSH;
            p = ((unsigned)s << BSH) | (unsigned)(d & (BNODES - 1));
            atomicAdd(&cnt[b], 1);
        }
        pay[idx] = ok ? p : 0xFFFFFFFFu;
        pbk[idx] = (unsigned short)b;
    }
    __syncthreads();
    for (int b = tid; b < nbuck; b += BKT_T) {
        int c = cnt[b];
        base[b] = c ? atomicAdd(gcur + b, c) : 0;
    }
    __syncthreads();
    for (int b = tid; b < nbuck; b += BKT_T) cnt[b] = 0;
    __syncthreads();

    // replay from LDS: chunk-merged cached stores
    #pragma unroll
    for (int k = 0; k < BEPT; ++k) {
        int idx = k * BKT_T + tid;
        unsigned p = pay[idx];
        if (p != 0xFFFFFFFFu) {
            int b = pbk[idx];
            int pos = base[b] + atomicAdd(&cnt[b], 1);
            if (pos < CAP) bkt[(size_t)b * CAP + pos] = p;
        }
    }
}

// ====== fused distrib + layer-1 agg + node2, LANE-PER-NODE ======
// 128 threads/block, one block per bucket. Build padded rows in LDS, then
// lane owns node: serial edge loop in registers, then serial 64-feature
// epilogue over an LDS weight table. No cross-lane ops at all.
__global__ __launch_bounds__(128)
void agg1t_kernel(const int* __restrict__ gcur, const unsigned* __restrict__ bkt,
                  const float2* __restrict__ x, const float4* __restrict__ consts,
                  const float* __restrict__ W1, const float* __restrict__ b1,
                  const float* __restrict__ W2, const float* __restrict__ as2,
                  const float* __restrict__ ad2, float4* __restrict__ pack2,
                  int N) {
    __shared__ int rows[BNODES * ROWP];    // 33.3 KB
    __shared__ int cur[BNODES];
    __shared__ float4 tab[64];             // {w1a, w1b, b1, w2a}
    __shared__ float w2bL[64];
    int b = blockIdx.x, tid = threadIdx.x;
    int nodeBase = b << BSH;
    cur[tid] = 0;
    if (tid < 64) {
        tab[tid] = make_float4(W1[2 * tid], W1[2 * tid + 1], b1[tid], W2[tid]);
        w2bL[tid] = W2[64 + tid];
    }
    __syncthreads();

    int cnt = gcur[b];
    if (cnt > CAP) cnt = CAP;
    const unsigned* bp = bkt + (size_t)b * CAP;
    for (int k = tid; k < cnt; k += 128) {
        unsigned p = bp[k];                // L2-resident payload
        int ld = p & (BNODES - 1);
        int r = atomicAdd(&cur[ld], 1);
        if (r < MAXDEG) rows[ld * ROWP + r] = (int)(p >> BSH);
    }
    __syncthreads();

    int i = tid;                           // lane-per-node (2 waves cover 128)
    int n = nodeBase + i;
    if (n >= N) return;
    int dg = cur[i];
    if (dg > MAXDEG) dg = MAXDEG;
    float4 c = *consts;
    float2 xn = x[n];                      // coalesced 8B
    float adst_n = fmaf(xn.x, c.z, xn.y * c.w);

    float sp = 0.f, s0 = 0.f, s1 = 0.f;
    for (int r = 0; r < dg; ++r) {
        int s = rows[i * ROWP + r];        // conflict-free (stride 65)
        float2 xs = x[s];                  // 8B gather, L2-resident
        float e = lrelu(fmaf(xs.x, c.x, xs.y * c.y) + adst_n);
        float pv = __expf(e);              // unshifted; softmax shift-invariant
        sp += pv;
        s0 = fmaf(pv, xs.x, s0);
        s1 = fmaf(pv, xs.y, s1);
    }
    float rden = 1.f / (sp + EPS);
    s0 *= rden;
    s1 *= rden;

    // node2 epilogue: per-lane serial over 64 features (uniform LDS reads)
    float q0 = 0.f, q1 = 0.f;
    #pragma unroll 8
    for (int j = 0; j < 64; ++j) {
        float4 t = tab[j];
        float hr = fmaxf(fmaf(t.x, s0, t.y * s1) + t.z, 0.f);
        q0 = fmaf(hr, t.w, q0);
        q1 = fmaf(hr, w2bL[j], q1);
    }
    float sa = as2[0], sb = as2[1], da = ad2[0], db = ad2[1];
    pack2[n] = make_float4(q0, q1,
                           fmaf(q0, sa, q1 * sb),
                           fmaf(q0, da, q1 * db));   // coalesced 16B
}

// ====== fused distrib + layer-2 agg + bias + log_softmax, LANE-PER-NODE ====
__global__ __launch_bounds__(128)
void agg2t_kernel(const int* __restrict__ gcur, const unsigned* __restrict__ bkt,
                  const float4* __restrict__ pack2, const float* __restrict__ b2,
                  float2* __restrict__ out, int N) {
    __shared__ int rows[BNODES * ROWP];    // 33.3 KB
    __shared__ int cur[BNODES];
    int b = blockIdx.x, tid = threadIdx.x;
    int nodeBase = b << BSH;
    cur[tid] = 0;
    __syncthreads();

    int cnt = gcur[b];
    if (cnt > CAP) cnt = CAP;
    const unsigned* bp = bkt + (size_t)b * CAP;
    for (int k = tid; k < cnt; k += 128) {
        unsigned p = bp[k];
        int ld = p & (BNODES - 1);
        int r = atomicAdd(&cur[ld], 1);
        if (r < MAXDEG) rows[ld * ROWP + r] = (int)(p >> BSH);
    }
    __syncthreads();

    int i = tid;
    int n = nodeBase + i;
    if (n >= N) return;
    int dg = cur[i];
    if (dg > MAXDEG) dg = MAXDEG;
    float adst_n = ((const float*)(pack2 + n))[3];   // coalesced strided read

    float sp = 0.f, a0 = 0.f, a1 = 0.f;
    for (int r = 0; r < dg; ++r) {
        int s = rows[i * ROWP + r];
        float4 P = pack2[s];               // 16B gather, L2-resident
        float pv = __expf(lrelu(P.z + adst_n));
        sp += pv;
        a0 = fmaf(pv, P.x, a0);
        a1 = fmaf(pv, P.y, a1);
    }
    float rd = 1.f / (sp + EPS);
    float v0 = fmaf(a0, rd, b2[0]);
    float v1 = fmaf(a1, rd, b2[1]);
    float mx = fmaxf(v0, v1);
    float lse = mx + logf(__expf(v0 - mx) + __expf(v1 - mx));
    out[n] = make_float2(v0 - lse, v1 - lse);        // coalesced 8B
}

extern "C" void kernel_launch(void* const* d_in, const int* in_sizes, int n_in,
                              void* d_out, int out_size, void* d_ws, size_t ws_size,
                              hipStream_t stream) {
    const float* x      = (const float*)d_in[0];
    const int*   eidx   = (const int*)d_in[1];
    const float* W1     = (const float*)d_in[2];
    const float* att_s1 = (const float*)d_in[3];
    const float* att_d1 = (const float*)d_in[4];
    const float* b1     = (const float*)d_in[5];
    const float* W2     = (const float*)d_in[6];
    const float* att_s2 = (const float*)d_in[7];
    const float* att_d2 = (const float*)d_in[8];
    const float* b2     = (const float*)d_in[9];

    const int N     = in_sizes[0] / 2;   // x is [N,2]
    const int E     = in_sizes[1] / 2;   // edge_index is [2,E]
    const int Etot  = E + N;             // + self loops
    const int nbuck = (N + BNODES - 1) >> BSH;   // 782 for N=100k (<= NBMAX)

    const int* src = eidx;
    const int* dst = eidx + E;

    // ---- workspace carve-up (16B aligned) ----
    char* w = (char*)(((uintptr_t)d_ws + 15) & ~(uintptr_t)15);
    int*      gcur   = (int*)w;      w += (size_t)NBMAX * 4;
    unsigned* bkt    = (unsigned*)w; w += (size_t)nbuck * CAP * 4;
    float4*   pack2  = (float4*)w;   w += (size_t)N * 16;
    float4*   consts = (float4*)w;   w += 16;

    // consts + gcur zeroing
    const_kernel<<<dim3(1), dim3(1024), 0, stream>>>(W1, att_s1, att_d1, consts, gcur);

    // ---- pass 1: bucket partition (16 waves/block, LDS payload staging) ----
    int nblocks = (Etot + BKT_T * BEPT - 1) / (BKT_T * BEPT);
    bucket_kernel<<<dim3(nblocks), dim3(BKT_T), 0, stream>>>(src, dst, gcur, bkt, E, Etot, nbuck);

    // ---- fused distrib + layer-1 agg + node2 (lane-per-node) ----
    agg1t_kernel<<<dim3(nbuck), dim3(128), 0, stream>>>(
        gcur, bkt, (const float2*)x, consts, W1, b1, W2, att_s2, att_d2, pack2, N);

    // ---- fused distrib + layer-2 agg + bias + log_softmax (lane-per-node) ----
    agg2t_kernel<<<dim3(nbuck), dim3(128), 0, stream>>>(
        gcur, bkt, pack2, b2, (float2*)d_out, N);
}